// Round 12
// baseline (260.879 us; speedup 1.0000x reference)
//
#include <hip/hip_runtime.h>

typedef _Float16 f16;
typedef _Float16 f16x2 __attribute__((ext_vector_type(2)));
typedef _Float16 f16x4 __attribute__((ext_vector_type(4)));
typedef _Float16 f16x8 __attribute__((ext_vector_type(8)));
typedef float f32x4 __attribute__((ext_vector_type(4)));
typedef float f32x16 __attribute__((ext_vector_type(16)));
typedef int i32x2 __attribute__((ext_vector_type(2)));
typedef int i32x4 __attribute__((ext_vector_type(4)));

#define B_   4
#define C_   256
#define N_   4096
#define OUT_ 256

// async global->LDS, 16B per lane, dest = wave-uniform base + lane*16
__device__ __forceinline__ void gld_lds16(const f16* g, f16* l) {
    __builtin_amdgcn_global_load_lds(
        (const __attribute__((address_space(1))) void*)g,
        (__attribute__((address_space(3))) void*)l, 16, 0, 0);
}

// r[0] = lo-half lane's value, r[1] = hi-half lane's value (VALU, no LDS)
__device__ __forceinline__ i32x2 perm32(int x) {
    return __builtin_amdgcn_permlane32_swap(x, x, false, false);
}
__device__ __forceinline__ i32x2 perm32f(float x) {
    return __builtin_amdgcn_permlane32_swap(__float_as_int(x), __float_as_int(x), false, false);
}
__device__ __forceinline__ int packh(float a, float b) {
    f16x2 w = { (f16)a, (f16)b };
    return *(int*)&w;
}

// ---------------------------------------------------------------------------
// Kernel A: transpose+convert x [B,C,N] f32 -> xt [B,N,C] f16, W -> Wt[o][c] f16,
// and zero the 512-float stats accumulator. Stores vectorized f16x4.
// ---------------------------------------------------------------------------
__global__ __launch_bounds__(256) void k_prep(const float* __restrict__ x,
                                              const float* __restrict__ W,
                                              f16* __restrict__ xt,
                                              f16* __restrict__ Wt,
                                              float* __restrict__ stats) {
    int bid = blockIdx.x;
    int t = threadIdx.x;
    if (bid < 1024) {
        int b  = bid >> 8;
        int ct = (bid >> 6) & 3;
        int nt = bid & 63;
        int c0 = ct * 64, n0 = nt * 64;
        __shared__ float tile[64][65];
        int nl = t & 63;
        int r0 = t >> 6;
        #pragma unroll
        for (int i = 0; i < 16; ++i) {
            int cl = i * 4 + r0;
            tile[cl][nl] = x[((b * C_ + c0 + cl) * N_) + n0 + nl];
        }
        __syncthreads();
        #pragma unroll
        for (int i = 0; i < 4; ++i) {
            int n  = i * 16 + (t >> 4);
            int c4 = (t & 15) * 4;
            f16x4 o = { (f16)tile[c4][n], (f16)tile[c4 + 1][n],
                        (f16)tile[c4 + 2][n], (f16)tile[c4 + 3][n] };
            *(f16x4*)&xt[((b * N_ + n0 + n) * C_) + c0 + c4] = o;
        }
    } else {
        int wb = bid - 1024;
        #pragma unroll
        for (int i = 0; i < 4; ++i) {
            int idx = wb * 1024 + i * 256 + t;
            int c = idx >> 8, o = idx & 255;
            Wt[o * C_ + c] = (f16)W[idx];
        }
        if (wb < 2) stats[wb * 256 + t] = 0.f;
    }
}

// ---------------------------------------------------------------------------
// Kernel B: support^T[b][o][m] = sum_c xt[b][m][c] * W[c][o]   (f16 out)
// ---------------------------------------------------------------------------
__global__ __launch_bounds__(256) void k_support(const f16* __restrict__ xt,
                                                 const f16* __restrict__ Wt,
                                                 f16* __restrict__ supT) {
    int bid0 = blockIdx.x;
    int bid = (bid0 & 7) * 128 + (bid0 >> 3);   // bijective, clusters b per XCD
    int b  = bid >> 8;
    int ot = (bid >> 6) & 3;
    int mt = bid & 63;
    int o0 = ot * 64, m0 = mt * 64;
    __shared__ __align__(16) f16 Ws[64][264];
    __shared__ __align__(16) f16 Xs[64][264];
    int t = threadIdx.x;
    int wave = t >> 6, lane = t & 63, q = lane >> 4, l15 = lane & 15;
    #pragma unroll
    for (int p = 0; p < 8; ++p) {
        int idx = p * 256 + t;
        int row = idx >> 5, ch = (idx & 31) * 8;
        *(uint4*)&Ws[row][ch] = *(const uint4*)&Wt[(o0 + row) * C_ + ch];
        *(uint4*)&Xs[row][ch] = *(const uint4*)&xt[((b * N_) + m0 + row) * C_ + ch];
    }
    __syncthreads();
    f32x4 acc[4] = {};
    #pragma unroll
    for (int kk = 0; kk < 8; ++kk) {
        f16x8 a = *(f16x8*)&Ws[16 * wave + l15][kk * 32 + q * 8];
        #pragma unroll
        for (int ct = 0; ct < 4; ++ct) {
            f16x8 bb = *(f16x8*)&Xs[16 * ct + l15][kk * 32 + q * 8];
            acc[ct] = __builtin_amdgcn_mfma_f32_16x16x32_f16(a, bb, acc[ct], 0, 0, 0);
        }
    }
    #pragma unroll
    for (int ct = 0; ct < 4; ++ct)
        #pragma unroll
        for (int r = 0; r < 4; ++r) {
            int og = o0 + 16 * wave + q * 4 + r;
            int mg = m0 + 16 * ct + l15;
            supT[((b * OUT_ + og) * N_) + mg] = (f16)acc[ct][r];
        }
}

// ---------------------------------------------------------------------------
// Kernel C: split-K flash, fixed-shift softmax, REGISTER-P PV — ONE barrier
// per iteration. Wave (mh,nh) computes S-quadrant [32m x 32n] (as before),
// then keeps P in registers: A-fragments for 32x32x16 PV are rebuilt via
// f16-pack + permlane32_swap (hi-half exchange) + cndmask — no Ps LDS, no
// barrier B. PV: O_partial[n=32nh..][o=0..255] over the wave's OWN m-half:
// 8 o-tiles x 2 k-chunks = 16 MFMA, V^T fragments (B-operand, lane=o) read
// directly from supT (L2-hot 32KB slab shared across the XCD).
// oacc = 8 x f32x16 = 128 VGPR (mh-partials); block stores TWO pieces
// (mh=0/1), each normalized by the half's l; tail merges 4 pieces.
// K double-buffered in LDS; stage K(t+1) right after barrier A(t) (K(t-1)
// reads provably retired there). Barriers/iter: 1.
// LDS: 64K Ks + 0.75K = 64.8 KB -> 2 blocks/CU (register-capped anyway).
// ---------------------------------------------------------------------------
__global__ __launch_bounds__(256) __attribute__((amdgpu_waves_per_eu(2, 2)))
void k_flash(const f16* __restrict__ xt,
             const f16* __restrict__ supT,
             f16* __restrict__ Op,
             float* __restrict__ Ml) {
    int bid0 = blockIdx.x;
    int wg = (bid0 & 7) * 64 + (bid0 >> 3);   // XCD x owns wg in [64x, 64x+64)
    int h  = wg >> 8;
    int b  = (wg >> 6) & 3;
    int nb = wg & 63;
    int n0 = nb * 64;

    __shared__ __align__(16) f16 KsL[2][64 * 256];  // 65536 B, swizzled content
    __shared__ float Lh[2][64];                     //   512 B
    __shared__ float Lt[64];                        //   256 B

    int t = threadIdx.x;
    int wave = t >> 6, lane = t & 63;
    int l31 = lane & 31, hi = lane >> 5;
    int nh = wave & 1, mh = wave >> 1;

    // Q fragments (B-operand of 32x32x16): row n = n0+32nh+l31, k-chunk 8*hi
    const f16* qbase = xt + ((size_t)(b * N_) + n0 + 32 * nh + l31) * C_ + 8 * hi;
    f16x8 qf[16];
    #pragma unroll
    for (int kc = 0; kc < 16; ++kc)
        qf[kc] = *(const f16x8*)&qbase[16 * kc];

    // fixed softmax shift m_fix = |q_n|^2 (identical across hi-pair, mh-waves,
    // and both split-K halves)
    float m_fix;
    {
        float s = 0.f;
        #pragma unroll
        for (int kc = 0; kc < 16; ++kc)
            #pragma unroll
            for (int j = 0; j < 8; ++j) {
                float v = (float)qf[kc][j];
                s += v * v;
            }
        i32x2 rr = perm32f(s);
        m_fix = __int_as_float(rr[0]) + __int_as_float(rr[1]);
    }

    f32x16 oacc[8] = {};   // [ot]: O_partial[n-rowmap][o = 32ot + l31]
    float l_run = 0.f;

    // K staging source offsets (pre-swizzled; linear LDS dest)
    const f16* kbase = xt + (size_t)b * N_ * C_;
    int c16 = (lane & 31) * 8;
    int rhalf = lane >> 5;
    int soff[8];
    #pragma unroll
    for (int j = 0; j < 8; ++j) {
        int row = wave * 16 + j * 2 + rhalf;
        soff[j] = row * 256 + (c16 ^ ((row & 7) << 3));
    }
    int swr = (l31 & 7) << 3;   // read-side swizzle (f16 units)

    // V^T fragment base: lane reads supT[(b*256 + 32*ot + l31)*N + m...]
    const f16* vbase = supT + ((size_t)(b * OUT_) + l31) * N_ + 32 * mh + 8 * hi;

    // prologue: stage K tile 0 into buffer 0
    {
        const f16* kt = kbase + (size_t)(h * 2048) * C_;
        #pragma unroll
        for (int j = 0; j < 8; ++j)
            gld_lds16(kt + soff[j], &KsL[0][wave * 4096 + j * 512]);
    }

    for (int it = 0; it < 32; ++it) {
        int m0 = h * 2048 + it * 64;

        // A (sole barrier): K[it] landed; all waves' K[it-1] LDS reads retired
        asm volatile("s_waitcnt vmcnt(0) lgkmcnt(0)" ::: "memory");
        __builtin_amdgcn_s_barrier();
        __builtin_amdgcn_sched_barrier(0);

        // stage K[it+1] into the other buffer (full iteration of slack)
        if (it < 31) {
            const f16* kt = kbase + (size_t)(m0 + 64) * C_;
            #pragma unroll
            for (int j = 0; j < 8; ++j)
                gld_lds16(kt + soff[j], &KsL[(it + 1) & 1][wave * 4096 + j * 512]);
        }

        // QK^T quadrant: 16 x mfma_32x32x16. A = K rows 32mh+l31, B = Q.
        // sacc[reg] = S[m_rel = (reg&3)+8(reg>>2)+4hi][n = 32nh + l31]
        f32x16 sacc = {};
        const f16* krow = &KsL[it & 1][(32 * mh + l31) * 256];
        __builtin_amdgcn_s_setprio(1);
        #pragma unroll
        for (int kc = 0; kc < 16; ++kc) {
            int col = (16 * kc + 8 * hi) ^ swr;
            f16x8 kf = *(const f16x8*)&krow[col];
            sacc = __builtin_amdgcn_mfma_f32_32x32x16_f16(kf, qf[kc], sacc, 0, 0, 0);
        }
        __builtin_amdgcn_s_setprio(0);

        // lane-local softmax
        float p[16];
        #pragma unroll
        for (int r = 0; r < 16; ++r)
            p[r] = __expf(sacc[r] - m_fix);
        float s0 = (p[0] + p[1]) + (p[2] + p[3]);
        float s1 = (p[4] + p[5]) + (p[6] + p[7]);
        float s2 = (p[8] + p[9]) + (p[10] + p[11]);
        float s3 = (p[12] + p[13]) + (p[14] + p[15]);
        l_run += (s0 + s1) + (s2 + s3);

        // Build PV A-fragments in-register. Lane holds P[m_rel][n=l31] with
        // m_rel = (reg&3)+8(reg>>2)+4hi. A-operand needs P[n=l31][m-chunk
        // 16kc2+8hi+0..7]: hi-half exchange via permlane32_swap.
        int U0 = packh(p[0], p[1]),   U1 = packh(p[2], p[3]);
        int U2 = packh(p[4], p[5]),   U3 = packh(p[6], p[7]);
        int U4 = packh(p[8], p[9]),   U5 = packh(p[10], p[11]);
        int U6 = packh(p[12], p[13]), U7 = packh(p[14], p[15]);
        i32x2 P0 = perm32(U0), P1 = perm32(U1), P2 = perm32(U2), P3 = perm32(U3);
        i32x2 P4 = perm32(U4), P5 = perm32(U5), P6 = perm32(U6), P7 = perm32(U7);
        bool hb = hi != 0;
        i32x4 pa0i = { hb ? P2[0] : P0[0], hb ? P3[0] : P1[0],
                       hb ? P2[1] : P0[1], hb ? P3[1] : P1[1] };
        i32x4 pa1i = { hb ? P6[0] : P4[0], hb ? P7[0] : P5[0],
                       hb ? P6[1] : P4[1], hb ? P7[1] : P5[1] };
        f16x8 pa0 = *(f16x8*)&pa0i;
        f16x8 pa1 = *(f16x8*)&pa1i;

        // PV: D[i=n][j=o] += P[n][m] V[m][o]; B = V^T frags straight from L2
        const f16* vb = vbase + m0;
        __builtin_amdgcn_s_setprio(1);
        #pragma unroll
        for (int ot = 0; ot < 8; ++ot) {
            f16x8 v0 = *(const f16x8*)&vb[(size_t)(32 * ot) * N_];
            f16x8 v1 = *(const f16x8*)&vb[(size_t)(32 * ot) * N_ + 16];
            oacc[ot] = __builtin_amdgcn_mfma_f32_32x32x16_f16(pa0, v0, oacc[ot], 0, 0, 0);
            oacc[ot] = __builtin_amdgcn_mfma_f32_32x32x16_f16(pa1, v1, oacc[ot], 0, 0, 0);
        }
        __builtin_amdgcn_s_setprio(0);
    }

    // epilogue: combine l partials (hi pair via permlane, mh pair via LDS)
    {
        i32x2 rr = perm32f(l_run);
        l_run = __int_as_float(rr[0]) + __int_as_float(rr[1]);
    }
    __syncthreads();
    if (lane < 32) Lh[mh][32 * nh + l31] = l_run;
    __syncthreads();
    if (t < 64) {
        float lt = Lh[0][t] + Lh[1][t];
        Lt[t] = 1.0f / fmaxf(lt, 1e-37f);   // cold half: l may underflow to 0
        Ml[(size_t)wg * 64 + t] = lt;
    }
    __syncthreads();

    // store piece (h, mh): rows n_loc = 32nh + 8g + 4hi + r, col o = 32ot+l31
    f16* Obase = Op + (size_t)((h * 2 + mh) * 256 + b * 64 + nb) * (64 * 256);
    #pragma unroll
    for (int g = 0; g < 4; ++g) {
        float4 lt4 = *(const float4*)&Lt[32 * nh + 8 * g + 4 * hi];
        #pragma unroll
        for (int r = 0; r < 4; ++r) {
            int n_loc = 32 * nh + 8 * g + 4 * hi + r;
            float sc = ((const float*)&lt4)[r];
            #pragma unroll
            for (int ot = 0; ot < 8; ++ot)
                Obase[n_loc * 256 + 32 * ot + l31] =
                    (f16)(oacc[ot][4 * g + r] * sc);
        }
    }
}

// ---------------------------------------------------------------------------
// Kernel D1 (k_mstats): merge 4 pieces + LeakyReLU -> BN partial sums ONLY.
// y = c1*(P0+P1) + c2*(P2+P3); pieces are l_half-normalized partials.
// ---------------------------------------------------------------------------
__global__ __launch_bounds__(256) void k_mstats(const f16* __restrict__ Op,
                                                const float* __restrict__ Ml,
                                                float* __restrict__ stats) {
    int bid0 = blockIdx.x;
    int bid = (bid0 & 7) * 128 + (bid0 >> 3);   // XCD clustering
    int b  = bid >> 8;
    int nb = (bid >> 2) & 63;
    int oq = bid & 3;
    int o0 = oq * 64;
    int t = threadIdx.x;
    const f16* Pc[4];
    #pragma unroll
    for (int pc = 0; pc < 4; ++pc)
        Pc[pc] = Op + (size_t)(pc * 256 + b * 64 + nb) * (64 * 256);
    const float* Ml1 = Ml + (size_t)(b * 64 + nb) * 64;
    const float* Ml2 = Ml + (size_t)(256 + b * 64 + nb) * 64;
    __shared__ float c1s[64], c2s[64];
    __shared__ float rs[8][64], rss[8][64];
    if (t < 64) {
        float l1 = Ml1[t], l2 = Ml2[t];
        float inv = 1.0f / (l1 + l2);
        c1s[t] = l1 * inv;
        c2s[t] = l2 * inv;
    }
    __syncthreads();
    int ow = (t & 31) * 2;
    int ng = t >> 5;
    float s0 = 0.f, s1 = 0.f, ss0 = 0.f, ss1 = 0.f;
    #pragma unroll
    for (int j = 0; j < 8; ++j) {
        int n = ng * 8 + j;
        f16x2 u0 = *(const f16x2*)&Pc[0][n * 256 + o0 + ow];
        f16x2 u1 = *(const f16x2*)&Pc[1][n * 256 + o0 + ow];
        f16x2 u2 = *(const f16x2*)&Pc[2][n * 256 + o0 + ow];
        f16x2 u3 = *(const f16x2*)&Pc[3][n * 256 + o0 + ow];
        float c1 = c1s[n], c2 = c2s[n];
        float v0 = c1 * ((float)u0[0] + (float)u1[0]) + c2 * ((float)u2[0] + (float)u3[0]);
        float v1 = c1 * ((float)u0[1] + (float)u1[1]) + c2 * ((float)u2[1] + (float)u3[1]);
        v0 = v0 >= 0.f ? v0 : 0.01f * v0;
        v1 = v1 >= 0.f ? v1 : 0.01f * v1;
        s0 += v0; ss0 += v0 * v0;
        s1 += v1; ss1 += v1 * v1;
    }
    rs[ng][ow] = s0;  rs[ng][ow + 1] = s1;
    rss[ng][ow] = ss0; rss[ng][ow + 1] = ss1;
    __syncthreads();
    if (t < 64) {
        float S = 0.f, SS = 0.f;
        #pragma unroll
        for (int g = 0; g < 8; ++g) { S += rs[g][t]; SS += rss[g][t]; }
        atomicAdd(&stats[o0 + t], S);
        atomicAdd(&stats[256 + o0 + t], SS);
    }
}

// ---------------------------------------------------------------------------
// Kernel D2 (k_mapply): recompute merged y (bit-identical), apply BN,
// transposed coalesced store of out.
// ---------------------------------------------------------------------------
__global__ __launch_bounds__(256) void k_mapply(const f16* __restrict__ Op,
                                                const float* __restrict__ Ml,
                                                const float* __restrict__ stats,
                                                const float* __restrict__ gamma,
                                                const float* __restrict__ beta,
                                                float* __restrict__ out) {
    int bid0 = blockIdx.x;
    int bid = (bid0 & 7) * 128 + (bid0 >> 3);   // XCD clustering
    int b  = bid >> 8;
    int nb = (bid >> 2) & 63;
    int oq = bid & 3;
    int n0 = nb * 64, o0 = oq * 64;
    int t = threadIdx.x;
    const f16* Pc[4];
    #pragma unroll
    for (int pc = 0; pc < 4; ++pc)
        Pc[pc] = Op + (size_t)(pc * 256 + b * 64 + nb) * (64 * 256);
    const float* Ml1 = Ml + (size_t)(b * 64 + nb) * 64;
    const float* Ml2 = Ml + (size_t)(256 + b * 64 + nb) * 64;
    __shared__ float c1s[64], c2s[64], gs[64], bs[64];
    __shared__ float tile[64][65];   // [o][n]
    if (t < 64) {
        float l1 = Ml1[t], l2 = Ml2[t];
        float inv = 1.0f / (l1 + l2);
        c1s[t] = l1 * inv;
        c2s[t] = l2 * inv;
        int o = o0 + t;
        float mean = stats[o] * (1.0f / 16384.0f);
        float var = stats[256 + o] * (1.0f / 16384.0f) - mean * mean;
        float rstd = rsqrtf(var + 1e-5f);
        float g = gamma[o] * rstd;
        gs[t] = g;
        bs[t] = beta[o] - mean * g;
    }
    __syncthreads();
    int ow = (t & 31) * 2;
    int ng = t >> 5;
    #pragma unroll
    for (int j = 0; j < 8; ++j) {
        int n = ng * 8 + j;
        f16x2 u0 = *(const f16x2*)&Pc[0][n * 256 + o0 + ow];
        f16x2 u1 = *(const f16x2*)&Pc[1][n * 256 + o0 + ow];
        f16x2 u2 = *(const f16x2*)&Pc[2][n * 256 + o0 + ow];
        f16x2 u3 = *(const f16x2*)&Pc[3][n * 256 + o0 + ow];
        float c1 = c1s[n], c2 = c2s[n];
        float v0 = c1 * ((float)u0[0] + (float)u1[0]) + c2 * ((float)u2[0] + (float)u3[0]);
        float v1 = c1 * ((float)u0[1] + (float)u1[1]) + c2 * ((float)u2[1] + (float)u3[1]);
        v0 = v0 >= 0.f ? v0 : 0.01f * v0;
        v1 = v1 >= 0.f ? v1 : 0.01f * v1;
        tile[ow][n]     = gs[ow] * v0 + bs[ow];
        tile[ow + 1][n] = gs[ow + 1] * v1 + bs[ow + 1];
    }
    __syncthreads();
    int w = t >> 6, lane = t & 63;
    float* dst = out + ((size_t)(b * OUT_ + o0)) * N_ + n0;
    #pragma unroll
    for (int k = 0; k < 16; ++k) {
        int o = 16 * w + k;
        dst[(size_t)o * N_ + lane] = tile[o][lane];
    }
}

extern "C" void kernel_launch(void* const* d_in, const int* in_sizes, int n_in,
                              void* d_out, int out_size, void* d_ws, size_t ws_size,
                              hipStream_t stream) {
    const float* x     = (const float*)d_in[0];
    const float* W     = (const float*)d_in[1];
    const float* gamma = (const float*)d_in[2];
    const float* beta  = (const float*)d_in[3];
    float* out = (float*)d_out;

    f16* xt    = (f16*)d_ws;                      // 8 MB
    f16* supT  = xt + (size_t)B_ * N_ * C_;       // 8 MB
    f16* Wt    = supT + (size_t)B_ * N_ * OUT_;   // 128 KB
    f16* Op    = Wt + C_ * OUT_;                  // 4 pieces * 8 MB = 32 MB
    float* Ml  = (float*)(Op + (size_t)4 * 256 * 64 * 256);  // 512*64 floats
    float* stats = Ml + (size_t)512 * 64;         // 512 floats: sum, sumsq

    k_prep<<<1088, 256, 0, stream>>>(x, W, xt, Wt, stats);
    k_support<<<1024, 256, 0, stream>>>(xt, Wt, supT);
    k_flash<<<512, 256, 0, stream>>>(xt, supT, Op, Ml);
    k_mstats<<<1024, 256, 0, stream>>>(Op, Ml, stats);
    k_mapply<<<1024, 256, 0, stream>>>(Op, Ml, stats, gamma, beta, out);
}

// Round 13
// 180.022 us; speedup vs baseline: 1.4491x; 1.4491x over previous
//
#include <hip/hip_runtime.h>

typedef _Float16 f16;
typedef _Float16 f16x2 __attribute__((ext_vector_type(2)));
typedef _Float16 f16x4 __attribute__((ext_vector_type(4)));
typedef _Float16 f16x8 __attribute__((ext_vector_type(8)));
typedef float f32x4 __attribute__((ext_vector_type(4)));
typedef float f32x16 __attribute__((ext_vector_type(16)));
typedef int i32x2 __attribute__((ext_vector_type(2)));

#define B_   4
#define C_   256
#define N_   4096
#define OUT_ 256

// async global->LDS, 16B per lane, dest = wave-uniform base + lane*16
__device__ __forceinline__ void gld_lds16(const f16* g, f16* l) {
    __builtin_amdgcn_global_load_lds(
        (const __attribute__((address_space(1))) void*)g,
        (__attribute__((address_space(3))) void*)l, 16, 0, 0);
}

// lane i<32 gets {x[i], x[i+32]}, lane i>=32 gets {x[i-32], x[i]} (VALU, no LDS)
__device__ __forceinline__ i32x2 perm32(float x) {
    return __builtin_amdgcn_permlane32_swap(__float_as_int(x), __float_as_int(x), false, false);
}

// ---------------------------------------------------------------------------
// Kernel A: transpose+convert x [B,C,N] f32 -> xt [B,N,C] f16, W -> Wt[o][c] f16,
// and zero the 512-float stats accumulator. Stores vectorized f16x4.
// ---------------------------------------------------------------------------
__global__ __launch_bounds__(256) void k_prep(const float* __restrict__ x,
                                              const float* __restrict__ W,
                                              f16* __restrict__ xt,
                                              f16* __restrict__ Wt,
                                              float* __restrict__ stats) {
    int bid = blockIdx.x;
    int t = threadIdx.x;
    if (bid < 1024) {
        int b  = bid >> 8;
        int ct = (bid >> 6) & 3;
        int nt = bid & 63;
        int c0 = ct * 64, n0 = nt * 64;
        __shared__ float tile[64][65];
        int nl = t & 63;
        int r0 = t >> 6;
        #pragma unroll
        for (int i = 0; i < 16; ++i) {
            int cl = i * 4 + r0;
            tile[cl][nl] = x[((b * C_ + c0 + cl) * N_) + n0 + nl];
        }
        __syncthreads();
        // store: thread covers c-quad (t&15)*4 at n = i*16 + (t>>4)
        #pragma unroll
        for (int i = 0; i < 4; ++i) {
            int n  = i * 16 + (t >> 4);
            int c4 = (t & 15) * 4;
            f16x4 o = { (f16)tile[c4][n], (f16)tile[c4 + 1][n],
                        (f16)tile[c4 + 2][n], (f16)tile[c4 + 3][n] };
            *(f16x4*)&xt[((b * N_ + n0 + n) * C_) + c0 + c4] = o;
        }
    } else {
        int wb = bid - 1024;
        #pragma unroll
        for (int i = 0; i < 4; ++i) {
            int idx = wb * 1024 + i * 256 + t;
            int c = idx >> 8, o = idx & 255;
            Wt[o * C_ + c] = (f16)W[idx];
        }
        if (wb < 2) stats[wb * 256 + t] = 0.f;
    }
}

// ---------------------------------------------------------------------------
// Kernel B: support^T[b][o][m] = sum_c xt[b][m][c] * W[c][o]   (f16 out)
// ---------------------------------------------------------------------------
__global__ __launch_bounds__(256) void k_support(const f16* __restrict__ xt,
                                                 const f16* __restrict__ Wt,
                                                 f16* __restrict__ supT) {
    int bid0 = blockIdx.x;
    int bid = (bid0 & 7) * 128 + (bid0 >> 3);   // bijective, clusters b per XCD
    int b  = bid >> 8;
    int ot = (bid >> 6) & 3;
    int mt = bid & 63;
    int o0 = ot * 64, m0 = mt * 64;
    __shared__ __align__(16) f16 Ws[64][264];
    __shared__ __align__(16) f16 Xs[64][264];
    int t = threadIdx.x;
    int wave = t >> 6, lane = t & 63, q = lane >> 4, l15 = lane & 15;
    #pragma unroll
    for (int p = 0; p < 8; ++p) {
        int idx = p * 256 + t;
        int row = idx >> 5, ch = (idx & 31) * 8;
        *(uint4*)&Ws[row][ch] = *(const uint4*)&Wt[(o0 + row) * C_ + ch];
        *(uint4*)&Xs[row][ch] = *(const uint4*)&xt[((b * N_) + m0 + row) * C_ + ch];
    }
    __syncthreads();
    f32x4 acc[4] = {};
    #pragma unroll
    for (int kk = 0; kk < 8; ++kk) {
        f16x8 a = *(f16x8*)&Ws[16 * wave + l15][kk * 32 + q * 8];
        #pragma unroll
        for (int ct = 0; ct < 4; ++ct) {
            f16x8 bb = *(f16x8*)&Xs[16 * ct + l15][kk * 32 + q * 8];
            acc[ct] = __builtin_amdgcn_mfma_f32_16x16x32_f16(a, bb, acc[ct], 0, 0, 0);
        }
    }
    #pragma unroll
    for (int ct = 0; ct < 4; ++ct)
        #pragma unroll
        for (int r = 0; r < 4; ++r) {
            int og = o0 + 16 * wave + q * 4 + r;
            int mg = m0 + 16 * ct + l15;
            supT[((b * OUT_ + og) * N_) + mg] = (f16)acc[ct][r];
        }
}

// ---------------------------------------------------------------------------
// Kernel C: split-K flash with FIXED per-column softmax shift — round-8/11
// proven configuration, with ONE change: the QK^T accumulator is split into
// TWO independent chains (even/odd k-chunks). The 16-MFMA serial chain on a
// single sacc was latency-bound (~32-40cyc latency vs ~8cyc throughput), and
// with occupancy register-pinned at 2 waves/SIMD the pipe idled ~70% inside
// the chain. 2 chains x 2 waves/SIMD = 4 in-flight MFMAs. +16 VGPR (~136).
// Everything else identical to round 11 (dbuf K, 2 barriers, Ps LDS, m_fix).
// ---------------------------------------------------------------------------
__global__ __launch_bounds__(256) __attribute__((amdgpu_waves_per_eu(2, 2)))
void k_flash(const f16* __restrict__ xt,
             const f16* __restrict__ supT,
             f16* __restrict__ Op,
             float* __restrict__ Ml) {
    int bid0 = blockIdx.x;
    int wg = (bid0 & 7) * 64 + (bid0 >> 3);   // XCD x owns wg in [64x, 64x+64)
    int h  = wg >> 8;
    int b  = (wg >> 6) & 3;
    int n0 = (wg & 63) * 64;

    __shared__ __align__(16) f16 KsL[2][64 * 256];  // 65536 B, swizzled content
    __shared__ __align__(16) f16 Ps[64][72];        //  9216 B
    __shared__ float Lh[2][64];                     //   512 B
    __shared__ float Lt[64];                        //   256 B -> 75520 B total

    int t = threadIdx.x;
    int wave = t >> 6, lane = t & 63;
    int q = lane >> 4, l15 = lane & 15;     // PV-side indices
    int l31 = lane & 31, hi = lane >> 5;    // QK^T-side indices
    int nh = wave & 1, mh = wave >> 1;

    const f16* qbase = xt + ((size_t)(b * N_) + n0 + 32 * nh + l31) * C_ + 8 * hi;
    f16x8 qf[16];
    #pragma unroll
    for (int kc = 0; kc < 16; ++kc)
        qf[kc] = *(const f16x8*)&qbase[16 * kc];

    // fixed softmax shift m_fix = |q_n|^2 (identical across hi-pair, mh-waves,
    // and both split-K halves)
    float m_fix;
    {
        float s = 0.f;
        #pragma unroll
        for (int kc = 0; kc < 16; ++kc)
            #pragma unroll
            for (int j = 0; j < 8; ++j) {
                float v = (float)qf[kc][j];
                s += v * v;
            }
        i32x2 rr = perm32(s);
        m_fix = __int_as_float(rr[0]) + __int_as_float(rr[1]);
    }

    f32x4 oacc[4][4] = {};
    float l_run = 0.f;

    const f16* kbase = xt + (size_t)b * N_ * C_;
    int c16 = (lane & 31) * 8;
    int rhalf = lane >> 5;
    int soff[8];
    #pragma unroll
    for (int j = 0; j < 8; ++j) {
        int row = wave * 16 + j * 2 + rhalf;
        soff[j] = row * 256 + (c16 ^ ((row & 7) << 3));
    }
    int swr = (l31 & 7) << 3;

    const f16* vbbase = supT + ((size_t)(b * OUT_) + 64 * wave + l15) * N_ + q * 8;

    {
        const f16* kt = kbase + (size_t)(h * 2048) * C_;
        #pragma unroll
        for (int j = 0; j < 8; ++j)
            gld_lds16(kt + soff[j], &KsL[0][wave * 4096 + j * 512]);
    }

    int cur = 0;
    for (int it = 0; it < 32; ++it) {
        int m0 = h * 2048 + it * 64;
        __syncthreads();   // A: K[it] landed; PV(it-1)'s Ps reads drained

        f16x8 vf[2][4];
        const f16* vb = vbbase + m0;
        #pragma unroll
        for (int ks = 0; ks < 2; ++ks)
            #pragma unroll
            for (int ot = 0; ot < 4; ++ot)
                vf[ks][ot] = *(const f16x8*)&vb[(size_t)(16 * ot) * N_ + ks * 32];

        if (it < 31) {
            const f16* kt = kbase + (size_t)(m0 + 64) * C_;
            #pragma unroll
            for (int j = 0; j < 8; ++j)
                gld_lds16(kt + soff[j], &KsL[cur ^ 1][wave * 4096 + j * 512]);
        }

        // QK^T quadrant: 16 x mfma_32x32x16 in TWO independent chains
        // (even kc -> sacc0, odd kc -> sacc1) to hide MFMA latency.
        f32x16 sacc0 = {}, sacc1 = {};
        const f16* krow = &KsL[cur][(32 * mh + l31) * 256];
        __builtin_amdgcn_s_setprio(1);
        #pragma unroll
        for (int kc = 0; kc < 16; kc += 2) {
            int col0 = (16 * kc + 8 * hi) ^ swr;
            int col1 = (16 * (kc + 1) + 8 * hi) ^ swr;
            f16x8 kf0 = *(const f16x8*)&krow[col0];
            f16x8 kf1 = *(const f16x8*)&krow[col1];
            sacc0 = __builtin_amdgcn_mfma_f32_32x32x16_f16(kf0, qf[kc], sacc0, 0, 0, 0);
            sacc1 = __builtin_amdgcn_mfma_f32_32x32x16_f16(kf1, qf[kc + 1], sacc1, 0, 0, 0);
        }
        __builtin_amdgcn_s_setprio(0);
        f32x16 sacc = sacc0 + sacc1;

        float p[16];
        #pragma unroll
        for (int r = 0; r < 16; ++r)
            p[r] = __expf(sacc[r] - m_fix);
        float s0 = (p[0] + p[1]) + (p[2] + p[3]);
        float s1 = (p[4] + p[5]) + (p[6] + p[7]);
        float s2 = (p[8] + p[9]) + (p[10] + p[11]);
        float s3 = (p[12] + p[13]) + (p[14] + p[15]);
        l_run += (s0 + s1) + (s2 + s3);

        #pragma unroll
        for (int g = 0; g < 4; ++g) {
            f16x4 pk = { (f16)p[4 * g], (f16)p[4 * g + 1],
                         (f16)p[4 * g + 2], (f16)p[4 * g + 3] };
            *(f16x4*)&Ps[32 * nh + l31][32 * mh + 8 * g + 4 * hi] = pk;
        }

        // B: light barrier — P visible; K/vf VMEM stays in flight
        asm volatile("s_waitcnt lgkmcnt(0)" ::: "memory");
        __builtin_amdgcn_s_barrier();
        __builtin_amdgcn_sched_barrier(0);

        __builtin_amdgcn_s_setprio(1);
        #pragma unroll
        for (int ks = 0; ks < 2; ++ks) {
            f16x8 af[4];
            #pragma unroll
            for (int nt = 0; nt < 4; ++nt)
                af[nt] = *(f16x8*)&Ps[16 * nt + l15][ks * 32 + q * 8];
            #pragma unroll
            for (int nt = 0; nt < 4; ++nt)
                #pragma unroll
                for (int ot = 0; ot < 4; ++ot)
                    oacc[nt][ot] = __builtin_amdgcn_mfma_f32_16x16x32_f16(af[nt], vf[ks][ot], oacc[nt][ot], 0, 0, 0);
        }
        __builtin_amdgcn_s_setprio(0);
        cur ^= 1;
    }

    {
        i32x2 rr = perm32(l_run);
        l_run = __int_as_float(rr[0]) + __int_as_float(rr[1]);
    }
    __syncthreads();
    if (lane < 32) Lh[mh][32 * nh + l31] = l_run;
    __syncthreads();
    if (t < 64) {
        float lt = Lh[0][t] + Lh[1][t];
        Lt[t] = 1.0f / fmaxf(lt, 1e-37f);   // cold half: l may be 0, oacc is 0
        Ml[(size_t)wg * 64 + t] = lt;
    }
    __syncthreads();

    float4 lv[4];
    #pragma unroll
    for (int nt = 0; nt < 4; ++nt)
        lv[nt] = *(const float4*)&Lt[16 * nt + 4 * q];

    f16* Obase = Op + (size_t)wg * (64 * 256);
    #pragma unroll
    for (int nt = 0; nt < 4; ++nt)
        #pragma unroll
        for (int ot = 0; ot < 4; ++ot)
            #pragma unroll
            for (int r = 0; r < 4; ++r) {
                int n = 16 * nt + q * 4 + r;
                int o = 64 * wave + 16 * ot + l15;
                Obase[n * 256 + o] = (f16)(oacc[nt][ot][r] * ((const float*)&lv[nt])[r]);
            }
}

// ---------------------------------------------------------------------------
// Kernel D1 (k_mstats): merge halves + LeakyReLU -> BN partial sums ONLY.
// No y store (y is recomputed in k_mapply). Reads Op (16MB), atomics out.
// ---------------------------------------------------------------------------
__global__ __launch_bounds__(256) void k_mstats(const f16* __restrict__ Op,
                                                const float* __restrict__ Ml,
                                                float* __restrict__ stats) {
    int bid0 = blockIdx.x;
    int bid = (bid0 & 7) * 128 + (bid0 >> 3);   // XCD clustering
    int b  = bid >> 8;
    int nb = (bid >> 2) & 63;
    int oq = bid & 3;
    int o0 = oq * 64;
    int t = threadIdx.x;
    const f16* O1 = Op + (size_t)(b * 64 + nb) * (64 * 256);
    const f16* O2 = Op + (size_t)(b * 64 + nb + 256) * (64 * 256);
    const float* Ml1 = Ml + (size_t)(b * 64 + nb) * 64;
    const float* Ml2 = Ml + (size_t)(b * 64 + nb + 256) * 64;
    __shared__ float c1s[64], c2s[64];
    __shared__ float rs[8][64], rss[8][64];
    if (t < 64) {
        float l1 = Ml1[t], l2 = Ml2[t];
        float inv = 1.0f / (l1 + l2);
        c1s[t] = l1 * inv;
        c2s[t] = l2 * inv;
    }
    __syncthreads();
    int ow = (t & 31) * 2;
    int ng = t >> 5;
    float s0 = 0.f, s1 = 0.f, ss0 = 0.f, ss1 = 0.f;
    #pragma unroll
    for (int j = 0; j < 8; ++j) {
        int n = ng * 8 + j;
        f16x2 u1 = *(const f16x2*)&O1[n * 256 + o0 + ow];
        f16x2 u2 = *(const f16x2*)&O2[n * 256 + o0 + ow];
        float c1 = c1s[n], c2 = c2s[n];
        float v0 = c1 * (float)u1[0] + c2 * (float)u2[0];
        float v1 = c1 * (float)u1[1] + c2 * (float)u2[1];
        v0 = v0 >= 0.f ? v0 : 0.01f * v0;
        v1 = v1 >= 0.f ? v1 : 0.01f * v1;
        s0 += v0; ss0 += v0 * v0;
        s1 += v1; ss1 += v1 * v1;
    }
    rs[ng][ow] = s0;  rs[ng][ow + 1] = s1;
    rss[ng][ow] = ss0; rss[ng][ow + 1] = ss1;
    __syncthreads();
    if (t < 64) {
        float S = 0.f, SS = 0.f;
        #pragma unroll
        for (int g = 0; g < 8; ++g) { S += rs[g][t]; SS += rss[g][t]; }
        atomicAdd(&stats[o0 + t], S);
        atomicAdd(&stats[256 + o0 + t], SS);
    }
}

// ---------------------------------------------------------------------------
// Kernel D2 (k_mapply): recompute merged y (bit-identical), apply BN,
// transposed coalesced store of out.
// ---------------------------------------------------------------------------
__global__ __launch_bounds__(256) void k_mapply(const f16* __restrict__ Op,
                                                const float* __restrict__ Ml,
                                                const float* __restrict__ stats,
                                                const float* __restrict__ gamma,
                                                const float* __restrict__ beta,
                                                float* __restrict__ out) {
    int bid0 = blockIdx.x;
    int bid = (bid0 & 7) * 128 + (bid0 >> 3);   // XCD clustering
    int b  = bid >> 8;
    int nb = (bid >> 2) & 63;
    int oq = bid & 3;
    int n0 = nb * 64, o0 = oq * 64;
    int t = threadIdx.x;
    const f16* O1 = Op + (size_t)(b * 64 + nb) * (64 * 256);
    const f16* O2 = Op + (size_t)(b * 64 + nb + 256) * (64 * 256);
    const float* Ml1 = Ml + (size_t)(b * 64 + nb) * 64;
    const float* Ml2 = Ml + (size_t)(b * 64 + nb + 256) * 64;
    __shared__ float c1s[64], c2s[64], gs[64], bs[64];
    __shared__ float tile[64][65];   // [o][n]
    if (t < 64) {
        float l1 = Ml1[t], l2 = Ml2[t];
        float inv = 1.0f / (l1 + l2);
        c1s[t] = l1 * inv;
        c2s[t] = l2 * inv;
        int o = o0 + t;
        float mean = stats[o] * (1.0f / 16384.0f);
        float var = stats[256 + o] * (1.0f / 16384.0f) - mean * mean;
        float rstd = rsqrtf(var + 1e-5f);
        float g = gamma[o] * rstd;
        gs[t] = g;
        bs[t] = beta[o] - mean * g;
    }
    __syncthreads();
    int ow = (t & 31) * 2;
    int ng = t >> 5;
    #pragma unroll
    for (int j = 0; j < 8; ++j) {
        int n = ng * 8 + j;
        f16x2 u1 = *(const f16x2*)&O1[n * 256 + o0 + ow];
        f16x2 u2 = *(const f16x2*)&O2[n * 256 + o0 + ow];
        float c1 = c1s[n], c2 = c2s[n];
        float v0 = c1 * (float)u1[0] + c2 * (float)u2[0];
        float v1 = c1 * (float)u1[1] + c2 * (float)u2[1];
        v0 = v0 >= 0.f ? v0 : 0.01f * v0;
        v1 = v1 >= 0.f ? v1 : 0.01f * v1;
        tile[ow][n]     = gs[ow] * v0 + bs[ow];
        tile[ow + 1][n] = gs[ow + 1] * v1 + bs[ow + 1];
    }
    __syncthreads();
    int w = t >> 6, lane = t & 63;
    float* dst = out + ((size_t)(b * OUT_ + o0)) * N_ + n0;
    #pragma unroll
    for (int k = 0; k < 16; ++k) {
        int o = 16 * w + k;
        dst[(size_t)o * N_ + lane] = tile[o][lane];
    }
}

extern "C" void kernel_launch(void* const* d_in, const int* in_sizes, int n_in,
                              void* d_out, int out_size, void* d_ws, size_t ws_size,
                              hipStream_t stream) {
    const float* x     = (const float*)d_in[0];
    const float* W     = (const float*)d_in[1];
    const float* gamma = (const float*)d_in[2];
    const float* beta  = (const float*)d_in[3];
    float* out = (float*)d_out;

    f16* xt    = (f16*)d_ws;                      // 8 MB
    f16* supT  = xt + (size_t)B_ * N_ * C_;       // 8 MB
    f16* Wt    = supT + (size_t)B_ * N_ * OUT_;   // 128 KB
    f16* Op    = Wt + C_ * OUT_;                  // 16 MB
    float* Ml  = (float*)(Op + (size_t)2 * 256 * 64 * 256);  // 512*64 floats
    float* stats = Ml + (size_t)512 * 128;        // 512 floats: sum, sumsq

    k_prep<<<1088, 256, 0, stream>>>(x, W, xt, Wt, stats);
    k_support<<<1024, 256, 0, stream>>>(xt, Wt, supT);
    k_flash<<<512, 256, 0, stream>>>(xt, supT, Op, Ml);
    k_mstats<<<1024, 256, 0, stream>>>(Op, Ml, stats);
    k_mapply<<<1024, 256, 0, stream>>>(Op, Ml, stats, gamma, beta, out);
}

// Round 14
// 179.457 us; speedup vs baseline: 1.4537x; 1.0031x over previous
//
#include <hip/hip_runtime.h>

typedef _Float16 f16;
typedef _Float16 f16x2 __attribute__((ext_vector_type(2)));
typedef _Float16 f16x4 __attribute__((ext_vector_type(4)));
typedef _Float16 f16x8 __attribute__((ext_vector_type(8)));
typedef float f32x4 __attribute__((ext_vector_type(4)));
typedef float f32x16 __attribute__((ext_vector_type(16)));
typedef int i32x2 __attribute__((ext_vector_type(2)));

#define B_   4
#define C_   256
#define N_   4096
#define OUT_ 256

// async global->LDS, 16B per lane, dest = wave-uniform base + lane*16
__device__ __forceinline__ void gld_lds16(const f16* g, f16* l) {
    __builtin_amdgcn_global_load_lds(
        (const __attribute__((address_space(1))) void*)g,
        (__attribute__((address_space(3))) void*)l, 16, 0, 0);
}

// lane i<32 gets {x[i], x[i+32]}, lane i>=32 gets {x[i-32], x[i]} (VALU, no LDS)
__device__ __forceinline__ i32x2 perm32(float x) {
    return __builtin_amdgcn_permlane32_swap(__float_as_int(x), __float_as_int(x), false, false);
}

// ---------------------------------------------------------------------------
// Kernel A: transpose+convert x [B,C,N] f32 -> xt [B,N,C] f16, W -> Wt[o][c] f16,
// and zero the 512-float stats accumulator. Stores vectorized f16x4.
// ---------------------------------------------------------------------------
__global__ __launch_bounds__(256) void k_prep(const float* __restrict__ x,
                                              const float* __restrict__ W,
                                              f16* __restrict__ xt,
                                              f16* __restrict__ Wt,
                                              float* __restrict__ stats) {
    int bid = blockIdx.x;
    int t = threadIdx.x;
    if (bid < 1024) {
        int b  = bid >> 8;
        int ct = (bid >> 6) & 3;
        int nt = bid & 63;
        int c0 = ct * 64, n0 = nt * 64;
        __shared__ float tile[64][65];
        int nl = t & 63;
        int r0 = t >> 6;
        #pragma unroll
        for (int i = 0; i < 16; ++i) {
            int cl = i * 4 + r0;
            tile[cl][nl] = x[((b * C_ + c0 + cl) * N_) + n0 + nl];
        }
        __syncthreads();
        // store: thread covers c-quad (t&15)*4 at n = i*16 + (t>>4)
        #pragma unroll
        for (int i = 0; i < 4; ++i) {
            int n  = i * 16 + (t >> 4);
            int c4 = (t & 15) * 4;
            f16x4 o = { (f16)tile[c4][n], (f16)tile[c4 + 1][n],
                        (f16)tile[c4 + 2][n], (f16)tile[c4 + 3][n] };
            *(f16x4*)&xt[((b * N_ + n0 + n) * C_) + c0 + c4] = o;
        }
    } else {
        int wb = bid - 1024;
        #pragma unroll
        for (int i = 0; i < 4; ++i) {
            int idx = wb * 1024 + i * 256 + t;
            int c = idx >> 8, o = idx & 255;
            Wt[o * C_ + c] = (f16)W[idx];
        }
        if (wb < 2) stats[wb * 256 + t] = 0.f;
    }
}

// ---------------------------------------------------------------------------
// Kernel B: support^T[b][o][m] = sum_c xt[b][m][c] * W[c][o]   (f16 out)
// ---------------------------------------------------------------------------
__global__ __launch_bounds__(256) void k_support(const f16* __restrict__ xt,
                                                 const f16* __restrict__ Wt,
                                                 f16* __restrict__ supT) {
    int bid0 = blockIdx.x;
    int bid = (bid0 & 7) * 128 + (bid0 >> 3);   // bijective, clusters b per XCD
    int b  = bid >> 8;
    int ot = (bid >> 6) & 3;
    int mt = bid & 63;
    int o0 = ot * 64, m0 = mt * 64;
    __shared__ __align__(16) f16 Ws[64][264];
    __shared__ __align__(16) f16 Xs[64][264];
    int t = threadIdx.x;
    int wave = t >> 6, lane = t & 63, q = lane >> 4, l15 = lane & 15;
    #pragma unroll
    for (int p = 0; p < 8; ++p) {
        int idx = p * 256 + t;
        int row = idx >> 5, ch = (idx & 31) * 8;
        *(uint4*)&Ws[row][ch] = *(const uint4*)&Wt[(o0 + row) * C_ + ch];
        *(uint4*)&Xs[row][ch] = *(const uint4*)&xt[((b * N_) + m0 + row) * C_ + ch];
    }
    __syncthreads();
    f32x4 acc[4] = {};
    #pragma unroll
    for (int kk = 0; kk < 8; ++kk) {
        f16x8 a = *(f16x8*)&Ws[16 * wave + l15][kk * 32 + q * 8];
        #pragma unroll
        for (int ct = 0; ct < 4; ++ct) {
            f16x8 bb = *(f16x8*)&Xs[16 * ct + l15][kk * 32 + q * 8];
            acc[ct] = __builtin_amdgcn_mfma_f32_16x16x32_f16(a, bb, acc[ct], 0, 0, 0);
        }
    }
    #pragma unroll
    for (int ct = 0; ct < 4; ++ct)
        #pragma unroll
        for (int r = 0; r < 4; ++r) {
            int og = o0 + 16 * wave + q * 4 + r;
            int mg = m0 + 16 * ct + l15;
            supT[((b * OUT_ + og) * N_) + mg] = (f16)acc[ct][r];
        }
}

// ---------------------------------------------------------------------------
// Kernel C: split-K flash with FIXED per-column softmax shift — round-11
// proven source (single sacc chain), plus ONE change: PHASE STAGGER.
// Co-resident partner blocks (bid0, bid0+256 share a CU under round-robin
// dispatch) run identical instruction streams launched simultaneously ->
// their barriers phase-lock and both waves on a SIMD stall together (~48%
// of wall, with MfmaUtil==work/wall==30% exactly at full MFMA throughput).
// Delaying the second cohort by ~half an iteration (~3584 cyc) interleaves
// the phases so one block's compute fills the other's barrier stalls.
// Safe: pure time shift, no math/order change (fixed-shift softmax has no
// cross-iteration state dependence).
// ---------------------------------------------------------------------------
__global__ __launch_bounds__(256) __attribute__((amdgpu_waves_per_eu(2, 2)))
void k_flash(const f16* __restrict__ xt,
             const f16* __restrict__ supT,
             f16* __restrict__ Op,
             float* __restrict__ Ml) {
    int bid0 = blockIdx.x;
    // phase-stagger the second-resident cohort by ~half an iteration
    if (bid0 & 256) __builtin_amdgcn_s_sleep(56);   // ~3584 cyc

    int wg = (bid0 & 7) * 64 + (bid0 >> 3);   // XCD x owns wg in [64x, 64x+64)
    int h  = wg >> 8;
    int b  = (wg >> 6) & 3;
    int n0 = (wg & 63) * 64;

    __shared__ __align__(16) f16 KsL[2][64 * 256];  // 65536 B, swizzled content
    __shared__ __align__(16) f16 Ps[64][72];        //  9216 B
    __shared__ float Lh[2][64];                     //   512 B
    __shared__ float Lt[64];                        //   256 B -> 75520 B total

    int t = threadIdx.x;
    int wave = t >> 6, lane = t & 63;
    int q = lane >> 4, l15 = lane & 15;     // PV-side indices
    int l31 = lane & 31, hi = lane >> 5;    // QK^T-side indices
    int nh = wave & 1, mh = wave >> 1;

    const f16* qbase = xt + ((size_t)(b * N_) + n0 + 32 * nh + l31) * C_ + 8 * hi;
    f16x8 qf[16];
    #pragma unroll
    for (int kc = 0; kc < 16; ++kc)
        qf[kc] = *(const f16x8*)&qbase[16 * kc];

    // fixed softmax shift m_fix = |q_n|^2 (identical across hi-pair, mh-waves,
    // and both split-K halves)
    float m_fix;
    {
        float s = 0.f;
        #pragma unroll
        for (int kc = 0; kc < 16; ++kc)
            #pragma unroll
            for (int j = 0; j < 8; ++j) {
                float v = (float)qf[kc][j];
                s += v * v;
            }
        i32x2 rr = perm32(s);
        m_fix = __int_as_float(rr[0]) + __int_as_float(rr[1]);
    }

    f32x4 oacc[4][4] = {};
    float l_run = 0.f;

    const f16* kbase = xt + (size_t)b * N_ * C_;
    int c16 = (lane & 31) * 8;
    int rhalf = lane >> 5;
    int soff[8];
    #pragma unroll
    for (int j = 0; j < 8; ++j) {
        int row = wave * 16 + j * 2 + rhalf;
        soff[j] = row * 256 + (c16 ^ ((row & 7) << 3));
    }
    int swr = (l31 & 7) << 3;

    const f16* vbbase = supT + ((size_t)(b * OUT_) + 64 * wave + l15) * N_ + q * 8;

    {
        const f16* kt = kbase + (size_t)(h * 2048) * C_;
        #pragma unroll
        for (int j = 0; j < 8; ++j)
            gld_lds16(kt + soff[j], &KsL[0][wave * 4096 + j * 512]);
    }

    int cur = 0;
    for (int it = 0; it < 32; ++it) {
        int m0 = h * 2048 + it * 64;
        __syncthreads();   // A: K[it] landed; PV(it-1)'s Ps reads drained

        f16x8 vf[2][4];
        const f16* vb = vbbase + m0;
        #pragma unroll
        for (int ks = 0; ks < 2; ++ks)
            #pragma unroll
            for (int ot = 0; ot < 4; ++ot)
                vf[ks][ot] = *(const f16x8*)&vb[(size_t)(16 * ot) * N_ + ks * 32];

        if (it < 31) {
            const f16* kt = kbase + (size_t)(m0 + 64) * C_;
            #pragma unroll
            for (int j = 0; j < 8; ++j)
                gld_lds16(kt + soff[j], &KsL[cur ^ 1][wave * 4096 + j * 512]);
        }

        // QK^T quadrant: 16 x mfma_32x32x16. A = K rows 32mh+l31, B = Q.
        // sacc[reg] = S[m = 32mh + (reg&3)+8(reg>>2)+4hi][n = 32nh + l31]
        f32x16 sacc = {};
        const f16* krow = &KsL[cur][(32 * mh + l31) * 256];
        __builtin_amdgcn_s_setprio(1);
        #pragma unroll
        for (int kc = 0; kc < 16; ++kc) {
            int col = (16 * kc + 8 * hi) ^ swr;
            f16x8 kf = *(const f16x8*)&krow[col];
            sacc = __builtin_amdgcn_mfma_f32_32x32x16_f16(kf, qf[kc], sacc, 0, 0, 0);
        }
        __builtin_amdgcn_s_setprio(0);

        float p[16];
        #pragma unroll
        for (int r = 0; r < 16; ++r)
            p[r] = __expf(sacc[r] - m_fix);
        float s0 = (p[0] + p[1]) + (p[2] + p[3]);
        float s1 = (p[4] + p[5]) + (p[6] + p[7]);
        float s2 = (p[8] + p[9]) + (p[10] + p[11]);
        float s3 = (p[12] + p[13]) + (p[14] + p[15]);
        l_run += (s0 + s1) + (s2 + s3);

        #pragma unroll
        for (int g = 0; g < 4; ++g) {
            f16x4 pk = { (f16)p[4 * g], (f16)p[4 * g + 1],
                         (f16)p[4 * g + 2], (f16)p[4 * g + 3] };
            *(f16x4*)&Ps[32 * nh + l31][32 * mh + 8 * g + 4 * hi] = pk;
        }

        // B: light barrier — P visible; K/vf VMEM stays in flight
        asm volatile("s_waitcnt lgkmcnt(0)" ::: "memory");
        __builtin_amdgcn_s_barrier();
        __builtin_amdgcn_sched_barrier(0);

        __builtin_amdgcn_s_setprio(1);
        #pragma unroll
        for (int ks = 0; ks < 2; ++ks) {
            f16x8 af[4];
            #pragma unroll
            for (int nt = 0; nt < 4; ++nt)
                af[nt] = *(f16x8*)&Ps[16 * nt + l15][ks * 32 + q * 8];
            #pragma unroll
            for (int nt = 0; nt < 4; ++nt)
                #pragma unroll
                for (int ot = 0; ot < 4; ++ot)
                    oacc[nt][ot] = __builtin_amdgcn_mfma_f32_16x16x32_f16(af[nt], vf[ks][ot], oacc[nt][ot], 0, 0, 0);
        }
        __builtin_amdgcn_s_setprio(0);
        cur ^= 1;
    }

    {
        i32x2 rr = perm32(l_run);
        l_run = __int_as_float(rr[0]) + __int_as_float(rr[1]);
    }
    __syncthreads();
    if (lane < 32) Lh[mh][32 * nh + l31] = l_run;
    __syncthreads();
    if (t < 64) {
        float lt = Lh[0][t] + Lh[1][t];
        Lt[t] = 1.0f / fmaxf(lt, 1e-37f);   // cold half: l may be 0, oacc is 0
        Ml[(size_t)wg * 64 + t] = lt;
    }
    __syncthreads();

    float4 lv[4];
    #pragma unroll
    for (int nt = 0; nt < 4; ++nt)
        lv[nt] = *(const float4*)&Lt[16 * nt + 4 * q];

    f16* Obase = Op + (size_t)wg * (64 * 256);
    #pragma unroll
    for (int nt = 0; nt < 4; ++nt)
        #pragma unroll
        for (int ot = 0; ot < 4; ++ot)
            #pragma unroll
            for (int r = 0; r < 4; ++r) {
                int n = 16 * nt + q * 4 + r;
                int o = 64 * wave + 16 * ot + l15;
                Obase[n * 256 + o] = (f16)(oacc[nt][ot][r] * ((const float*)&lv[nt])[r]);
            }
}

// ---------------------------------------------------------------------------
// Kernel D1 (k_mstats): merge halves + LeakyReLU -> BN partial sums ONLY.
// No y store (y is recomputed in k_mapply). Reads Op (16MB), atomics out.
// ---------------------------------------------------------------------------
__global__ __launch_bounds__(256) void k_mstats(const f16* __restrict__ Op,
                                                const float* __restrict__ Ml,
                                                float* __restrict__ stats) {
    int bid0 = blockIdx.x;
    int bid = (bid0 & 7) * 128 + (bid0 >> 3);   // XCD clustering
    int b  = bid >> 8;
    int nb = (bid >> 2) & 63;
    int oq = bid & 3;
    int o0 = oq * 64;
    int t = threadIdx.x;
    const f16* O1 = Op + (size_t)(b * 64 + nb) * (64 * 256);
    const f16* O2 = Op + (size_t)(b * 64 + nb + 256) * (64 * 256);
    const float* Ml1 = Ml + (size_t)(b * 64 + nb) * 64;
    const float* Ml2 = Ml + (size_t)(b * 64 + nb + 256) * 64;
    __shared__ float c1s[64], c2s[64];
    __shared__ float rs[8][64], rss[8][64];
    if (t < 64) {
        float l1 = Ml1[t], l2 = Ml2[t];
        float inv = 1.0f / (l1 + l2);
        c1s[t] = l1 * inv;
        c2s[t] = l2 * inv;
    }
    __syncthreads();
    int ow = (t & 31) * 2;
    int ng = t >> 5;
    float s0 = 0.f, s1 = 0.f, ss0 = 0.f, ss1 = 0.f;
    #pragma unroll
    for (int j = 0; j < 8; ++j) {
        int n = ng * 8 + j;
        f16x2 u1 = *(const f16x2*)&O1[n * 256 + o0 + ow];
        f16x2 u2 = *(const f16x2*)&O2[n * 256 + o0 + ow];
        float c1 = c1s[n], c2 = c2s[n];
        float v0 = c1 * (float)u1[0] + c2 * (float)u2[0];
        float v1 = c1 * (float)u1[1] + c2 * (float)u2[1];
        v0 = v0 >= 0.f ? v0 : 0.01f * v0;
        v1 = v1 >= 0.f ? v1 : 0.01f * v1;
        s0 += v0; ss0 += v0 * v0;
        s1 += v1; ss1 += v1 * v1;
    }
    rs[ng][ow] = s0;  rs[ng][ow + 1] = s1;
    rss[ng][ow] = ss0; rss[ng][ow + 1] = ss1;
    __syncthreads();
    if (t < 64) {
        float S = 0.f, SS = 0.f;
        #pragma unroll
        for (int g = 0; g < 8; ++g) { S += rs[g][t]; SS += rss[g][t]; }
        atomicAdd(&stats[o0 + t], S);
        atomicAdd(&stats[256 + o0 + t], SS);
    }
}

// ---------------------------------------------------------------------------
// Kernel D2 (k_mapply): recompute merged y (bit-identical), apply BN,
// transposed coalesced store of out.
// ---------------------------------------------------------------------------
__global__ __launch_bounds__(256) void k_mapply(const f16* __restrict__ Op,
                                                const float* __restrict__ Ml,
                                                const float* __restrict__ stats,
                                                const float* __restrict__ gamma,
                                                const float* __restrict__ beta,
                                                float* __restrict__ out) {
    int bid0 = blockIdx.x;
    int bid = (bid0 & 7) * 128 + (bid0 >> 3);   // XCD clustering
    int b  = bid >> 8;
    int nb = (bid >> 2) & 63;
    int oq = bid & 3;
    int n0 = nb * 64, o0 = oq * 64;
    int t = threadIdx.x;
    const f16* O1 = Op + (size_t)(b * 64 + nb) * (64 * 256);
    const f16* O2 = Op + (size_t)(b * 64 + nb + 256) * (64 * 256);
    const float* Ml1 = Ml + (size_t)(b * 64 + nb) * 64;
    const float* Ml2 = Ml + (size_t)(b * 64 + nb + 256) * 64;
    __shared__ float c1s[64], c2s[64], gs[64], bs[64];
    __shared__ float tile[64][65];   // [o][n]
    if (t < 64) {
        float l1 = Ml1[t], l2 = Ml2[t];
        float inv = 1.0f / (l1 + l2);
        c1s[t] = l1 * inv;
        c2s[t] = l2 * inv;
        int o = o0 + t;
        float mean = stats[o] * (1.0f / 16384.0f);
        float var = stats[256 + o] * (1.0f / 16384.0f) - mean * mean;
        float rstd = rsqrtf(var + 1e-5f);
        float g = gamma[o] * rstd;
        gs[t] = g;
        bs[t] = beta[o] - mean * g;
    }
    __syncthreads();
    int ow = (t & 31) * 2;
    int ng = t >> 5;
    #pragma unroll
    for (int j = 0; j < 8; ++j) {
        int n = ng * 8 + j;
        f16x2 u1 = *(const f16x2*)&O1[n * 256 + o0 + ow];
        f16x2 u2 = *(const f16x2*)&O2[n * 256 + o0 + ow];
        float c1 = c1s[n], c2 = c2s[n];
        float v0 = c1 * (float)u1[0] + c2 * (float)u2[0];
        float v1 = c1 * (float)u1[1] + c2 * (float)u2[1];
        v0 = v0 >= 0.f ? v0 : 0.01f * v0;
        v1 = v1 >= 0.f ? v1 : 0.01f * v1;
        tile[ow][n]     = gs[ow] * v0 + bs[ow];
        tile[ow + 1][n] = gs[ow + 1] * v1 + bs[ow + 1];
    }
    __syncthreads();
    int w = t >> 6, lane = t & 63;
    float* dst = out + ((size_t)(b * OUT_ + o0)) * N_ + n0;
    #pragma unroll
    for (int k = 0; k < 16; ++k) {
        int o = 16 * w + k;
        dst[(size_t)o * N_ + lane] = tile[o][lane];
    }
}

extern "C" void kernel_launch(void* const* d_in, const int* in_sizes, int n_in,
                              void* d_out, int out_size, void* d_ws, size_t ws_size,
                              hipStream_t stream) {
    const float* x     = (const float*)d_in[0];
    const float* W     = (const float*)d_in[1];
    const float* gamma = (const float*)d_in[2];
    const float* beta  = (const float*)d_in[3];
    float* out = (float*)d_out;

    f16* xt    = (f16*)d_ws;                      // 8 MB
    f16* supT  = xt + (size_t)B_ * N_ * C_;       // 8 MB
    f16* Wt    = supT + (size_t)B_ * N_ * OUT_;   // 128 KB
    f16* Op    = Wt + C_ * OUT_;                  // 16 MB
    float* Ml  = (float*)(Op + (size_t)2 * 256 * 64 * 256);  // 512*64 floats
    float* stats = Ml + (size_t)512 * 128;        // 512 floats: sum, sumsq

    k_prep<<<1088, 256, 0, stream>>>(x, W, xt, Wt, stats);
    k_support<<<1024, 256, 0, stream>>>(xt, Wt, supT);
    k_flash<<<512, 256, 0, stream>>>(xt, supT, Op, Ml);
    k_mstats<<<1024, 256, 0, stream>>>(Op, Ml, stats);
    k_mapply<<<1024, 256, 0, stream>>>(Op, Ml, stats, gamma, beta, out);
}